// Round 6
// baseline (1175.186 us; speedup 1.0000x reference)
//
#include <hip/hip_runtime.h>

#define D 32
#define NPB 64                      // nodes per fused block (dst-local fits 6 bits)
#define SRC_BITS 25
#define SRC_MASK ((1 << SRC_BITS) - 1)
#define SCAN_CHUNK 1024
#define PKCAP 2048                  // staged srcpk per block (mean EB=1024, Poisson)
#define TILE 16                     // edges per DMA tile
#define NSLOT 3                     // LDS staging ring depth per wave

__device__ __forceinline__ float relu_f(float v) { return v > 0.f ? v : 0.f; }

__device__ __forceinline__ unsigned bf16_rne(float f) {
    unsigned u = __float_as_uint(f);
    return (u + 0x7FFFu + ((u >> 16) & 1u)) >> 16;
}

// async global->LDS: 16B per lane; global src per-lane, LDS dest wave-uniform
// (HW adds lane*16 itself — m03/m97/m104 semantics).
__device__ __forceinline__ void async16(const void* g, void* l) {
    __builtin_amdgcn_global_load_lds(
        (const __attribute__((address_space(1))) void*)g,
        (__attribute__((address_space(3))) void*)l, 16, 0, 0);
}

// ============================ preprocessing =============================
__global__ void __launch_bounds__(256) hist_kernel(
    const int* __restrict__ dst, int* __restrict__ deg, int E)
{
    int e = blockIdx.x * 256 + threadIdx.x;
    if (e < E) atomicAdd(&deg[dst[e]], 1);
}

__global__ void __launch_bounds__(256) scan_partial_kernel(
    const int* __restrict__ deg, int* __restrict__ part, int N)
{
    __shared__ int s[256];
    int t = threadIdx.x;
    int base = blockIdx.x * SCAN_CHUNK + t * 4;
    int sum = 0;
    #pragma unroll
    for (int i = 0; i < 4; ++i) { int idx = base + i; if (idx < N) sum += deg[idx]; }
    s[t] = sum;
    __syncthreads();
    for (int off = 128; off > 0; off >>= 1) {
        if (t < off) s[t] += s[t + off];
        __syncthreads();
    }
    if (t == 0) part[blockIdx.x] = s[0];
}

__global__ void scan_part_exclusive_kernel(int* part, int nb)
{
    if (threadIdx.x == 0 && blockIdx.x == 0) {
        int run = 0;
        for (int i = 0; i < nb; ++i) { int v = part[i]; part[i] = run; run += v; }
    }
}

__global__ void __launch_bounds__(256) scan_final_kernel(
    int* __restrict__ rowdeg, const int* __restrict__ part, int N)
{
    __shared__ int s[256];
    int t = threadIdx.x;
    int base = blockIdx.x * SCAN_CHUNK + t * 4;
    int d0 = 0, d1 = 0, d2 = 0, d3 = 0;
    if (base + 0 < N) d0 = rowdeg[base + 0];
    if (base + 1 < N) d1 = rowdeg[base + 1];
    if (base + 2 < N) d2 = rowdeg[base + 2];
    if (base + 3 < N) d3 = rowdeg[base + 3];
    int tsum = d0 + d1 + d2 + d3;
    s[t] = tsum;
    __syncthreads();
    for (int off = 1; off < 256; off <<= 1) {
        int a = (t >= off) ? s[t - off] : 0;
        __syncthreads();
        s[t] += a;
        __syncthreads();
    }
    int excl = s[t] - tsum + part[blockIdx.x];
    if (base + 0 < N) rowdeg[base + 0] = excl;
    if (base + 1 < N) rowdeg[base + 1] = excl + d0;
    if (base + 2 < N) rowdeg[base + 2] = excl + d0 + d1;
    if (base + 3 < N) rowdeg[base + 3] = excl + d0 + d1 + d2;
}

// R4's proven combined placement (122us): 8 threads/edge; lane 0 claims slot
// (row[] exclusive -> inclusive) + writes packed src|dstlocal; ea row
// converted to bf16 and written to sorted slot (uint2 index pos*8+q).
__global__ void __launch_bounds__(256) place_full_kernel(
    const int* __restrict__ src, const int* __restrict__ dst,
    const float* __restrict__ ea, int* __restrict__ row,
    int* __restrict__ srcpk, unsigned* __restrict__ eah, int E)
{
    int i = blockIdx.x * 256 + threadIdx.x;
    if (i >= E * 8) return;
    int e = i >> 3, q = i & 7;
    int pos = 0;
    if (q == 0) {
        int d = dst[e];
        pos = atomicAdd(&row[d], 1);
        srcpk[pos] = src[e] | ((d & (NPB - 1)) << SRC_BITS);
    }
    pos = __shfl(pos, 0, 8);
    float4 v = reinterpret_cast<const float4*>(ea)[(size_t)e * 8 + q];
    uint2 w;
    w.x = bf16_rne(v.x) | (bf16_rne(v.y) << 16);
    w.y = bf16_rne(v.z) | (bf16_rne(v.w) << 16);
    reinterpret_cast<uint2*>(eah)[(size_t)pos * 8 + q] = w;
}

__global__ void __launch_bounds__(256) place_csr_kernel(
    const int* __restrict__ src, const int* __restrict__ dst,
    int* __restrict__ row, int* __restrict__ srcperm,
    int* __restrict__ eperm, int E)
{
    int e = blockIdx.x * 256 + threadIdx.x;
    if (e < E) {
        int pos = atomicAdd(&row[dst[e]], 1);
        srcperm[pos] = src[e] | ((dst[e] & (NPB - 1)) << SRC_BITS);
        eperm[pos] = e;
    }
}

// ========================= fused layer (v5) ============================
// Edge phase pipelined via global_load_lds: per wave, tiles of 16 edges;
// each tile = 3 DMAs (1KB eah stream + 2x1KB x-row gathers, per-lane global
// src, linear LDS dest). 3-slot ring, counted vmcnt (6 steady) keeps 2
// tiles in flight per wave with zero VGPR payload. srcpk staged once in
// LDS so DMA addressing resolves via fast ds_read. Compute: segmented
// register accumulation + LDS-atomic flush (as R4). MLP in-block (as R4).
__global__ void __launch_bounds__(256) gine_fused5_kernel(
    const float* __restrict__ x, const uint2* __restrict__ eah,
    const int* __restrict__ srcpk, const int* __restrict__ row,
    const float* __restrict__ W1, const float* __restrict__ b1,
    const float* __restrict__ W2, const float* __restrict__ b2,
    const float* __restrict__ eps, int l, float* __restrict__ out, int N)
{
    __shared__ float W1s[D * D], W2s[D * D], b1s[D], b2s[D];
    __shared__ float aggr[NPB][D];          // 8KB
    __shared__ float ys[8][D];
    __shared__ int   pkL[PKCAP];            // 8KB
    __shared__ __align__(16) char stg[4][NSLOT][3072]; // 36KB: [1KB eah|2KB x]

    int t = threadIdx.x;
    int n0 = blockIdx.x * NPB;
    int nlast = min(n0 + NPB - 1, N - 1);
    int estart = n0 ? row[n0 - 1] : 0;      // row[] is inclusive prefix
    int eend   = row[nlast];
    int EB = eend - estart;
    int staged = min(EB, PKCAP);

    for (int i = t; i < D * D; i += 256) { W1s[i] = W1[i]; W2s[i] = W2[i]; }
    if (t < D) { b1s[t] = b1[t]; b2s[t] = b2[t]; }
    for (int i = t; i < NPB * D; i += 256) ((float*)aggr)[i] = 0.f;
    for (int i = t; i < staged; i += 256) pkL[i] = srcpk[estart + i];
    __syncthreads();

    int wv = t >> 6;                        // wave 0..3
    int ln = t & 63;                        // lane in wave
    int g  = (t >> 3) & 7;                 // 8-lane group in wave
    int q  = t & 7;                         // lane in group: features 4q..4q+3

    // wave's contiguous share of the staged edges
    int cw = (staged + 3) >> 2;
    int a0 = min(wv * cw, staged);
    int b0 = min(a0 + cw, staged);
    int nt = (b0 - a0) >> 4;                // full 16-edge tiles

    float4 acc = make_float4(0.f, 0.f, 0.f, 0.f);
    int cur = -1;

    auto flush = [&]() {
        if (cur >= 0) {
            atomicAdd(&aggr[cur][q * 4 + 0], acc.x);
            atomicAdd(&aggr[cur][q * 4 + 1], acc.y);
            atomicAdd(&aggr[cur][q * 4 + 2], acc.z);
            atomicAdd(&aggr[cur][q * 4 + 3], acc.w);
        }
    };
    auto edge = [&](int ld, uint2 w, float4 xv) {
        if (ld != cur) {
            flush();
            cur = ld;
            acc = make_float4(0.f, 0.f, 0.f, 0.f);
        }
        acc.x += relu_f(xv.x + __uint_as_float(w.x << 16));
        acc.y += relu_f(xv.y + __uint_as_float(w.x & 0xFFFF0000u));
        acc.z += relu_f(xv.z + __uint_as_float(w.y << 16));
        acc.w += relu_f(xv.w + __uint_as_float(w.y & 0xFFFF0000u));
    };

    auto stage = [&](int tt) {
        int kk = estart + a0 + tt * TILE;       // global edge index
        char* sl = stg[wv][tt % NSLOT];
        // eah: linear 1KB copy (lane ln -> bytes ln*16)
        async16((const char*)eah + (size_t)kk * 64 + ln * 16, sl);
        // x rows: 2 calls x 8 edges; lane ln: edge c*8+(ln>>3), part ln&7
        #pragma unroll
        for (int c = 0; c < 2; ++c) {
            int pk = pkL[a0 + tt * TILE + c * 8 + (ln >> 3)];
            async16((const char*)x + (size_t)(pk & SRC_MASK) * 128 + (ln & 7) * 16,
                    sl + 1024 + c * 1024);
        }
    };
    auto compute = [&](int tt) {
        int kk0 = a0 + tt * TILE;
        const char* sl = stg[wv][tt % NSLOT];
        #pragma unroll
        for (int c = 0; c < 2; ++c) {
            int pk = pkL[kk0 + c * 8 + g];
            uint2  w  = *reinterpret_cast<const uint2*>(sl + (c * 8 + g) * 64 + q * 8);
            float4 xv = *reinterpret_cast<const float4*>(sl + 1024 + c * 1024 + g * 128 + q * 16);
            edge((pk >> SRC_BITS) & (NPB - 1), w, xv);
        }
    };

    // -------- pipelined main loop --------
    if (nt > 0) stage(0);
    if (nt > 1) stage(1);
    for (int tt = 0; tt < nt; ++tt) {
        if (tt + 2 < nt) {
            stage(tt + 2);
            asm volatile("s_waitcnt vmcnt(6)" ::: "memory"); // tile tt's 3 DMAs done
        } else if (tt + 1 < nt) {
            asm volatile("s_waitcnt vmcnt(3)" ::: "memory");
        } else {
            asm volatile("s_waitcnt vmcnt(0)" ::: "memory");
        }
        compute(tt);
    }

    // -------- tails (global reads; ~3% of edges) --------
    auto tail = [&](int lo, int hi) {       // local idx in [lo,hi)
        for (int e = lo + g; e < hi; e += 8) {
            int pk = srcpk[estart + e];
            uint2 w = eah[(size_t)(estart + e) * 8 + q];
            float4 xv = *reinterpret_cast<const float4*>(x + (size_t)(pk & SRC_MASK) * D + q * 4);
            edge((pk >> SRC_BITS) & (NPB - 1), w, xv);
        }
    };
    tail(a0 + nt * TILE, b0);
    if (EB > staged) {                       // overflow (never for this input)
        int ovn = EB - staged;
        int c2 = (ovn + 3) >> 2;
        int o0 = staged + min(wv * c2, ovn);
        int o1 = min(o0 + c2, EB);
        tail(o0, o1);
    }
    flush();
    __syncthreads();

    // -------- MLP: half-wave hw owns nodes hw*8 .. hw*8+7 --------
    int hw = t >> 5, j = t & 31;
    float ep1 = 1.0f + eps[l];
    for (int r = 0; r < 8; ++r) {
        int ln2 = hw * 8 + r;
        int n = n0 + ln2;
        if (n >= N) break;                  // no barriers below: safe
        float h = ep1 * x[(size_t)n * D + j] + aggr[ln2][j];
        aggr[ln2][j] = h;                   // stage for broadcast reads
        float a1 = b1s[j];
        #pragma unroll
        for (int kk = 0; kk < D; ++kk)
            a1 = fmaf(aggr[ln2][kk], W1s[kk * D + j], a1);
        float y = relu_f(a1);
        ys[hw][j] = y;
        float a2 = b2s[j];
        #pragma unroll
        for (int kk = 0; kk < D; ++kk)
            a2 = fmaf(ys[hw][kk], W2s[kk * D + j], a2);
        out[(size_t)n * D + j] = relu_f(a2);
    }
}

// ================= fallback fused kernel (CSR gather path) =============
__global__ void __launch_bounds__(256) gine_fused_kernel(
    const float* __restrict__ x, const float* __restrict__ ea,
    const int* __restrict__ srcperm, const int* __restrict__ eperm,
    const int* __restrict__ row,
    const float* __restrict__ W1, const float* __restrict__ b1,
    const float* __restrict__ W2, const float* __restrict__ b2,
    const float* __restrict__ eps, int l, float* __restrict__ out, int N)
{
    __shared__ float W1s[D * D], W2s[D * D], b1s[D], b2s[D];
    int t = threadIdx.x;
    for (int i = t; i < D * D; i += 256) { W1s[i] = W1[i]; W2s[i] = W2[i]; }
    if (t < D) { b1s[t] = b1[t]; b2s[t] = b2[t]; }
    __syncthreads();

    int g = t >> 5, j = t & 31;
    int node = blockIdx.x * 8 + g;
    if (node >= N) return;
    int start = node ? row[node - 1] : 0;
    int end = row[node];

    float acc = 0.f;
    for (int k = start; k < end; ++k) {
        int s0 = srcperm[k] & SRC_MASK;
        float e0 = ea[(size_t)eperm[k] * D + j];
        acc += relu_f(x[(size_t)s0 * D + j] + e0);
    }
    float h = (1.0f + eps[l]) * x[(size_t)node * D + j] + acc;
    float a1 = b1s[j];
    #pragma unroll
    for (int kk = 0; kk < D; ++kk)
        a1 = fmaf(__shfl(h, kk, 32), W1s[kk * D + j], a1);
    float y = relu_f(a1);
    float a2 = b2s[j];
    #pragma unroll
    for (int kk = 0; kk < D; ++kk)
        a2 = fmaf(__shfl(y, kk, 32), W2s[kk * D + j], a2);
    out[(size_t)node * D + j] = relu_f(a2);
}

// ===================== atomic fallback path ====================
__global__ void __launch_bounds__(256) gine_scatter_kernel(
    const float* __restrict__ x, const float* __restrict__ ea,
    const int* __restrict__ src, const int* __restrict__ dst,
    float* __restrict__ aggr, int E)
{
    int i = blockIdx.x * blockDim.x + threadIdx.x;
    if (i >= E * 8) return;
    int e = i >> 3, q = i & 7;
    float4 a = reinterpret_cast<const float4*>(ea)[(size_t)e * 8 + q];
    int s = src[e], d = dst[e];
    float4 xv = reinterpret_cast<const float4*>(x)[(size_t)s * 8 + q];
    float* base = aggr + (size_t)d * D + (size_t)q * 4;
    __hip_atomic_fetch_add(base + 0, relu_f(xv.x + a.x), __ATOMIC_RELAXED, __HIP_MEMORY_SCOPE_AGENT);
    __hip_atomic_fetch_add(base + 1, relu_f(xv.y + a.y), __ATOMIC_RELAXED, __HIP_MEMORY_SCOPE_AGENT);
    __hip_atomic_fetch_add(base + 2, relu_f(xv.z + a.z), __ATOMIC_RELAXED, __HIP_MEMORY_SCOPE_AGENT);
    __hip_atomic_fetch_add(base + 3, relu_f(xv.w + a.w), __ATOMIC_RELAXED, __HIP_MEMORY_SCOPE_AGENT);
}

__global__ void __launch_bounds__(256) gine_node_kernel(
    const float* __restrict__ x, const float* __restrict__ aggr,
    const float* __restrict__ W1, const float* __restrict__ b1,
    const float* __restrict__ W2, const float* __restrict__ b2,
    const float* __restrict__ eps, int l, float* __restrict__ out, int N)
{
    __shared__ float W1s[D * D], W2s[D * D], b1s[D], b2s[D];
    __shared__ float hs[8][D], y1s[8][D];
    int t = threadIdx.x;
    for (int i = t; i < D * D; i += 256) { W1s[i] = W1[i]; W2s[i] = W2[i]; }
    if (t < D) { b1s[t] = b1[t]; b2s[t] = b2[t]; }
    float ep1 = 1.0f + eps[l];
    int local = t >> 5, j = t & 31;
    int node = blockIdx.x * 8 + local;
    __syncthreads();
    if (node < N)
        hs[local][j] = ep1 * x[(size_t)node * D + j] + aggr[(size_t)node * D + j];
    __syncthreads();
    if (node < N) {
        float acc = b1s[j];
        #pragma unroll
        for (int k = 0; k < D; ++k) acc = fmaf(hs[local][k], W1s[k * D + j], acc);
        y1s[local][j] = relu_f(acc);
    }
    __syncthreads();
    if (node < N) {
        float acc = b2s[j];
        #pragma unroll
        for (int k = 0; k < D; ++k) acc = fmaf(y1s[local][k], W2s[k * D + j], acc);
        out[(size_t)node * D + j] = relu_f(acc);
    }
}

// ============================== launcher ===============================
extern "C" void kernel_launch(void* const* d_in, const int* in_sizes, int n_in,
                              void* d_out, int out_size, void* d_ws, size_t ws_size,
                              hipStream_t stream) {
    const float* x_in = (const float*)d_in[0];
    const float* ea   = (const float*)d_in[1];
    const int*   ei   = (const int*)d_in[2];
    const float* W1   = (const float*)d_in[3];
    const float* b1   = (const float*)d_in[4];
    const float* W2   = (const float*)d_in[5];
    const float* b2   = (const float*)d_in[6];
    const float* eps  = (const float*)d_in[7];

    int N = in_sizes[0] / D;
    int E = in_sizes[1] / D;
    int L = in_sizes[3] / (D * D);

    const int* src = ei;       // edge_index[0] = message source j
    const int* dst = ei + E;   // edge_index[1] = message target i

    float* out = (float*)d_out;
    char*  ws  = (char*)d_ws;

    size_t off = 0;
    auto take = [&](size_t bytes) -> size_t {
        size_t p = off; off = (off + bytes + 255) & ~(size_t)255; return p;
    };
    size_t o_bufA    = take((size_t)N * D * sizeof(float));
    size_t o_row     = take((size_t)(N + 8) * sizeof(int));
    size_t o_part    = take(1024 * sizeof(int));
    size_t o_srcpk   = take((size_t)E * sizeof(int));
    size_t o_eperm   = take((size_t)E * sizeof(int));
    size_t need_csr  = off;
    size_t o_eah     = take((size_t)E * D * sizeof(unsigned short));
    size_t need_full = off;

    float* bufA  = (float*)(ws + o_bufA);
    int*   row   = (int*)(ws + o_row);
    int*   part  = (int*)(ws + o_part);
    int*   srcpk = (int*)(ws + o_srcpk);
    int*   eperm = (int*)(ws + o_eperm);

    int path = (ws_size >= need_full) ? 2 : (ws_size >= need_csr ? 1 : 0);

    if (path == 0) {
        float* aggr = bufA + (size_t)N * D;   // legacy path (needs 2*N*D)
        const float* cur = x_in;
        for (int l = 0; l < L; ++l) {
            float* nxt = (((L - 1 - l) & 1) == 0) ? out : bufA;
            hipMemsetAsync(aggr, 0, (size_t)N * D * sizeof(float), stream);
            gine_scatter_kernel<<<(E * 8 + 255) / 256, 256, 0, stream>>>(cur, ea, src, dst, aggr, E);
            gine_node_kernel<<<(N + 7) / 8, 256, 0, stream>>>(
                cur, aggr, W1 + (size_t)l * D * D, b1 + (size_t)l * D,
                W2 + (size_t)l * D * D, b2 + (size_t)l * D, eps, l, nxt, N);
            cur = nxt;
        }
        return;
    }

    unsigned* eah = (unsigned*)(ws + o_eah);

    // ---- preprocessing (once per call) ----
    int nb = (N + SCAN_CHUNK - 1) / SCAN_CHUNK;
    hipMemsetAsync(row, 0, (size_t)N * sizeof(int), stream);
    hist_kernel<<<(E + 255) / 256, 256, 0, stream>>>(dst, row, E);
    scan_partial_kernel<<<nb, 256, 0, stream>>>(row, part, N);
    scan_part_exclusive_kernel<<<1, 64, 0, stream>>>(part, nb);
    scan_final_kernel<<<nb, 256, 0, stream>>>(row, part, N);
    if (path == 2) {
        place_full_kernel<<<(E * 8 + 255) / 256, 256, 0, stream>>>(
            src, dst, ea, row, srcpk, eah, E);
    } else {
        place_csr_kernel<<<(E + 255) / 256, 256, 0, stream>>>(
            src, dst, row, srcpk, eperm, E);
    }
    // row[n] is now the inclusive prefix (end offset of node n)

    const float* cur = x_in;
    for (int l = 0; l < L; ++l) {
        float* nxt = (((L - 1 - l) & 1) == 0) ? out : bufA;
        if (path == 2) {
            gine_fused5_kernel<<<(N + NPB - 1) / NPB, 256, 0, stream>>>(
                cur, (const uint2*)eah, srcpk, row,
                W1 + (size_t)l * D * D, b1 + (size_t)l * D,
                W2 + (size_t)l * D * D, b2 + (size_t)l * D, eps, l, nxt, N);
        } else {
            gine_fused_kernel<<<(N + 7) / 8, 256, 0, stream>>>(
                cur, ea, srcpk, eperm, row,
                W1 + (size_t)l * D * D, b1 + (size_t)l * D,
                W2 + (size_t)l * D * D, b2 + (size_t)l * D, eps, l, nxt, N);
        }
        cur = nxt;
    }
}

// Round 7
// 515.540 us; speedup vs baseline: 2.2795x; 2.2795x over previous
//
#include <hip/hip_runtime.h>

#define D 32
#define NPB 64                      // nodes per fused block (dst-local fits 6 bits)
#define SRC_BITS 25
#define SRC_MASK ((1 << SRC_BITS) - 1)
#define SCAN_CHUNK 1024
#define PKCAP 2048                  // staged srcpk per block (mean EB=1024)

__device__ __forceinline__ float relu_f(float v) { return v > 0.f ? v : 0.f; }

__device__ __forceinline__ unsigned bf16_rne(float f) {
    unsigned u = __float_as_uint(f);
    return (u + 0x7FFFu + ((u >> 16) & 1u)) >> 16;
}

// ============================ preprocessing =============================
__global__ void __launch_bounds__(256) hist_kernel(
    const int* __restrict__ dst, int* __restrict__ deg, int E)
{
    int e = blockIdx.x * 256 + threadIdx.x;
    if (e < E) atomicAdd(&deg[dst[e]], 1);
}

__global__ void __launch_bounds__(256) scan_partial_kernel(
    const int* __restrict__ deg, int* __restrict__ part, int N)
{
    __shared__ int s[256];
    int t = threadIdx.x;
    int base = blockIdx.x * SCAN_CHUNK + t * 4;
    int sum = 0;
    #pragma unroll
    for (int i = 0; i < 4; ++i) { int idx = base + i; if (idx < N) sum += deg[idx]; }
    s[t] = sum;
    __syncthreads();
    for (int off = 128; off > 0; off >>= 1) {
        if (t < off) s[t] += s[t + off];
        __syncthreads();
    }
    if (t == 0) part[blockIdx.x] = s[0];
}

__global__ void scan_part_exclusive_kernel(int* part, int nb)
{
    if (threadIdx.x == 0 && blockIdx.x == 0) {
        int run = 0;
        for (int i = 0; i < nb; ++i) { int v = part[i]; part[i] = run; run += v; }
    }
}

__global__ void __launch_bounds__(256) scan_final_kernel(
    int* __restrict__ rowdeg, const int* __restrict__ part, int N)
{
    __shared__ int s[256];
    int t = threadIdx.x;
    int base = blockIdx.x * SCAN_CHUNK + t * 4;
    int d0 = 0, d1 = 0, d2 = 0, d3 = 0;
    if (base + 0 < N) d0 = rowdeg[base + 0];
    if (base + 1 < N) d1 = rowdeg[base + 1];
    if (base + 2 < N) d2 = rowdeg[base + 2];
    if (base + 3 < N) d3 = rowdeg[base + 3];
    int tsum = d0 + d1 + d2 + d3;
    s[t] = tsum;
    __syncthreads();
    for (int off = 1; off < 256; off <<= 1) {
        int a = (t >= off) ? s[t - off] : 0;
        __syncthreads();
        s[t] += a;
        __syncthreads();
    }
    int excl = s[t] - tsum + part[blockIdx.x];
    if (base + 0 < N) rowdeg[base + 0] = excl;
    if (base + 1 < N) rowdeg[base + 1] = excl + d0;
    if (base + 2 < N) rowdeg[base + 2] = excl + d0 + d1;
    if (base + 3 < N) rowdeg[base + 3] = excl + d0 + d1 + d2;
}

// R4's proven combined placement (~122us): 8 threads/edge; lane 0 claims slot
// (row[] exclusive -> inclusive) + writes packed src|dstlocal; ea row
// converted to bf16 and written to sorted slot (uint2 index pos*8+q).
__global__ void __launch_bounds__(256) place_full_kernel(
    const int* __restrict__ src, const int* __restrict__ dst,
    const float* __restrict__ ea, int* __restrict__ row,
    int* __restrict__ srcpk, unsigned* __restrict__ eah, int E)
{
    int i = blockIdx.x * 256 + threadIdx.x;
    if (i >= E * 8) return;
    int e = i >> 3, q = i & 7;
    int pos = 0;
    if (q == 0) {
        int d = dst[e];
        pos = atomicAdd(&row[d], 1);
        srcpk[pos] = src[e] | ((d & (NPB - 1)) << SRC_BITS);
    }
    pos = __shfl(pos, 0, 8);
    float4 v = reinterpret_cast<const float4*>(ea)[(size_t)e * 8 + q];
    uint2 w;
    w.x = bf16_rne(v.x) | (bf16_rne(v.y) << 16);
    w.y = bf16_rne(v.z) | (bf16_rne(v.w) << 16);
    reinterpret_cast<uint2*>(eah)[(size_t)pos * 8 + q] = w;
}

__global__ void __launch_bounds__(256) place_csr_kernel(
    const int* __restrict__ src, const int* __restrict__ dst,
    int* __restrict__ row, int* __restrict__ srcperm,
    int* __restrict__ eperm, int E)
{
    int e = blockIdx.x * 256 + threadIdx.x;
    if (e < E) {
        int pos = atomicAdd(&row[dst[e]], 1);
        srcperm[pos] = src[e] | ((dst[e] & (NPB - 1)) << SRC_BITS);
        eperm[pos] = e;
    }
}

// ========================= fused layer (v6) ============================
// R4's fused4 structure (32x 8-lane groups, segmented register accumulation,
// LDS-atomic flush) + two latency fixes:
//  (1) srcpk slice staged in LDS once per block (coalesced) -> per-batch
//      index fetch is a ~120cy broadcast ds_read, not a ~300-900cy global.
//  (2) explicit register double-buffer (batch=4, static A/B arrays): batch
//      n+1's eah+x loads issue before batch n's compute.
__global__ void __launch_bounds__(256, 4) gine_fused6_kernel(
    const float* __restrict__ x, const uint2* __restrict__ eah,
    const int* __restrict__ srcpk, const int* __restrict__ row,
    const float* __restrict__ W1, const float* __restrict__ b1,
    const float* __restrict__ W2, const float* __restrict__ b2,
    const float* __restrict__ eps, int l, float* __restrict__ out, int N)
{
    __shared__ float aggr[NPB][D];          // 8KB
    __shared__ float W1s[D * D], W2s[D * D];
    __shared__ float b1s[D], b2s[D];
    __shared__ float ys[8][D];
    __shared__ int   pkL[PKCAP];            // 8KB

    int t = threadIdx.x;
    int n0 = blockIdx.x * NPB;
    int nlast = min(n0 + NPB - 1, N - 1);
    int estart = n0 ? row[n0 - 1] : 0;      // row[] is inclusive prefix
    int eend   = row[nlast];
    int EB = eend - estart;
    int staged = min(EB, PKCAP);

    for (int i = t; i < D * D; i += 256) { W1s[i] = W1[i]; W2s[i] = W2[i]; }
    if (t < D) { b1s[t] = b1[t]; b2s[t] = b2[t]; }
    for (int i = t; i < NPB * D; i += 256) ((float*)aggr)[i] = 0.f;
    for (int i = t; i < staged; i += 256) pkL[i] = srcpk[estart + i];
    __syncthreads();

    int g8 = t >> 3;                        // group 0..31
    int q  = t & 7;                         // lane in group; owns features 4q..4q+3

    // group's contiguous share of the staged edges
    int chunk = (staged + 31) >> 5;
    int a = min(g8 * chunk, staged);
    int b = min(a + chunk, staged);

    float4 acc = make_float4(0.f, 0.f, 0.f, 0.f);
    int cur = -1;

    auto flush = [&]() {
        if (cur >= 0) {
            atomicAdd(&aggr[cur][q * 4 + 0], acc.x);
            atomicAdd(&aggr[cur][q * 4 + 1], acc.y);
            atomicAdd(&aggr[cur][q * 4 + 2], acc.z);
            atomicAdd(&aggr[cur][q * 4 + 3], acc.w);
        }
    };
    auto edge = [&](int ld, uint2 w, float4 xv) {
        if (ld != cur) {
            flush();
            cur = ld;
            acc = make_float4(0.f, 0.f, 0.f, 0.f);
        }
        acc.x += relu_f(xv.x + __uint_as_float(w.x << 16));
        acc.y += relu_f(xv.y + __uint_as_float(w.x & 0xFFFF0000u));
        acc.z += relu_f(xv.z + __uint_as_float(w.y << 16));
        acc.w += relu_f(xv.w + __uint_as_float(w.y & 0xFFFF0000u));
    };

    uint2  wA[4], wB[4];
    float4 xA[4], xB[4];
    int    pA[4], pB[4];

    // base = LOCAL staged index of batch start (global edge = estart + base)
    auto loadA = [&](int base) {
        #pragma unroll
        for (int i = 0; i < 4; ++i) {
            int p = pkL[base + i];           // LDS broadcast within group
            pA[i] = p;
            wA[i] = eah[(size_t)(estart + base + i) * 8 + q];
            xA[i] = *reinterpret_cast<const float4*>(x + (size_t)(p & SRC_MASK) * D + q * 4);
        }
    };
    auto loadB = [&](int base) {
        #pragma unroll
        for (int i = 0; i < 4; ++i) {
            int p = pkL[base + i];
            pB[i] = p;
            wB[i] = eah[(size_t)(estart + base + i) * 8 + q];
            xB[i] = *reinterpret_cast<const float4*>(x + (size_t)(p & SRC_MASK) * D + q * 4);
        }
    };
    auto computeA = [&]() {
        #pragma unroll
        for (int i = 0; i < 4; ++i)
            edge((pA[i] >> SRC_BITS) & (NPB - 1), wA[i], xA[i]);
    };
    auto computeB = [&]() {
        #pragma unroll
        for (int i = 0; i < 4; ++i)
            edge((pB[i] >> SRC_BITS) & (NPB - 1), wB[i], xB[i]);
    };

    int nfull = (b - a) >> 2;               // full 4-edge batches
    int k = a;
    if (nfull > 0) loadA(k);
    int i = 0;
    for (; i + 2 <= nfull; i += 2) {
        loadB(k + 4);                       // prefetch odd batch
        computeA();
        if (i + 2 < nfull) loadA(k + 8);    // prefetch next even batch
        computeB();
        k += 8;
    }
    if (i < nfull) { computeA(); k += 4; }

    // tail edges [k, b) + (astronomically rare) overflow beyond PKCAP
    for (int e = k; e < b; ++e) {
        int p = pkL[e];
        uint2 w = eah[(size_t)(estart + e) * 8 + q];
        float4 xv = *reinterpret_cast<const float4*>(x + (size_t)(p & SRC_MASK) * D + q * 4);
        edge((p >> SRC_BITS) & (NPB - 1), w, xv);
    }
    if (EB > staged) {
        int ovn = EB - staged;
        int c2 = (ovn + 31) >> 5;
        int o0 = staged + min(g8 * c2, ovn);
        int o1 = min(o0 + c2, EB);
        for (int e = o0; e < o1; ++e) {
            int p = srcpk[estart + e];
            uint2 w = eah[(size_t)(estart + e) * 8 + q];
            float4 xv = *reinterpret_cast<const float4*>(x + (size_t)(p & SRC_MASK) * D + q * 4);
            edge((p >> SRC_BITS) & (NPB - 1), w, xv);
        }
    }
    flush();
    __syncthreads();

    // -------- MLP: half-wave hw owns nodes hw*8 .. hw*8+7 --------
    int hw = t >> 5, j = t & 31;
    float ep1 = 1.0f + eps[l];
    for (int r = 0; r < 8; ++r) {
        int ln = hw * 8 + r;
        int n = n0 + ln;
        if (n >= N) break;                  // no barriers below: safe
        float h = ep1 * x[(size_t)n * D + j] + aggr[ln][j];
        aggr[ln][j] = h;                    // stage for broadcast reads
        float a1 = b1s[j];
        #pragma unroll
        for (int kk = 0; kk < D; ++kk)
            a1 = fmaf(aggr[ln][kk], W1s[kk * D + j], a1);
        float y = relu_f(a1);
        ys[hw][j] = y;
        float a2 = b2s[j];
        #pragma unroll
        for (int kk = 0; kk < D; ++kk)
            a2 = fmaf(ys[hw][kk], W2s[kk * D + j], a2);
        out[(size_t)n * D + j] = relu_f(a2);
    }
}

// ================= fallback fused kernel (CSR gather path) =============
__global__ void __launch_bounds__(256) gine_fused_kernel(
    const float* __restrict__ x, const float* __restrict__ ea,
    const int* __restrict__ srcperm, const int* __restrict__ eperm,
    const int* __restrict__ row,
    const float* __restrict__ W1, const float* __restrict__ b1,
    const float* __restrict__ W2, const float* __restrict__ b2,
    const float* __restrict__ eps, int l, float* __restrict__ out, int N)
{
    __shared__ float W1s[D * D], W2s[D * D], b1s[D], b2s[D];
    int t = threadIdx.x;
    for (int i = t; i < D * D; i += 256) { W1s[i] = W1[i]; W2s[i] = W2[i]; }
    if (t < D) { b1s[t] = b1[t]; b2s[t] = b2[t]; }
    __syncthreads();

    int g = t >> 5, j = t & 31;
    int node = blockIdx.x * 8 + g;
    if (node >= N) return;
    int start = node ? row[node - 1] : 0;
    int end = row[node];

    float acc = 0.f;
    for (int k = start; k < end; ++k) {
        int s0 = srcperm[k] & SRC_MASK;
        float e0 = ea[(size_t)eperm[k] * D + j];
        acc += relu_f(x[(size_t)s0 * D + j] + e0);
    }
    float h = (1.0f + eps[l]) * x[(size_t)node * D + j] + acc;
    float a1 = b1s[j];
    #pragma unroll
    for (int kk = 0; kk < D; ++kk)
        a1 = fmaf(__shfl(h, kk, 32), W1s[kk * D + j], a1);
    float y = relu_f(a1);
    float a2 = b2s[j];
    #pragma unroll
    for (int kk = 0; kk < D; ++kk)
        a2 = fmaf(__shfl(y, kk, 32), W2s[kk * D + j], a2);
    out[(size_t)node * D + j] = relu_f(a2);
}

// ===================== atomic fallback path ====================
__global__ void __launch_bounds__(256) gine_scatter_kernel(
    const float* __restrict__ x, const float* __restrict__ ea,
    const int* __restrict__ src, const int* __restrict__ dst,
    float* __restrict__ aggr, int E)
{
    int i = blockIdx.x * blockDim.x + threadIdx.x;
    if (i >= E * 8) return;
    int e = i >> 3, q = i & 7;
    float4 a = reinterpret_cast<const float4*>(ea)[(size_t)e * 8 + q];
    int s = src[e], d = dst[e];
    float4 xv = reinterpret_cast<const float4*>(x)[(size_t)s * 8 + q];
    float* base = aggr + (size_t)d * D + (size_t)q * 4;
    __hip_atomic_fetch_add(base + 0, relu_f(xv.x + a.x), __ATOMIC_RELAXED, __HIP_MEMORY_SCOPE_AGENT);
    __hip_atomic_fetch_add(base + 1, relu_f(xv.y + a.y), __ATOMIC_RELAXED, __HIP_MEMORY_SCOPE_AGENT);
    __hip_atomic_fetch_add(base + 2, relu_f(xv.z + a.z), __ATOMIC_RELAXED, __HIP_MEMORY_SCOPE_AGENT);
    __hip_atomic_fetch_add(base + 3, relu_f(xv.w + a.w), __ATOMIC_RELAXED, __HIP_MEMORY_SCOPE_AGENT);
}

__global__ void __launch_bounds__(256) gine_node_kernel(
    const float* __restrict__ x, const float* __restrict__ aggr,
    const float* __restrict__ W1, const float* __restrict__ b1,
    const float* __restrict__ W2, const float* __restrict__ b2,
    const float* __restrict__ eps, int l, float* __restrict__ out, int N)
{
    __shared__ float W1s[D * D], W2s[D * D], b1s[D], b2s[D];
    __shared__ float hs[8][D], y1s[8][D];
    int t = threadIdx.x;
    for (int i = t; i < D * D; i += 256) { W1s[i] = W1[i]; W2s[i] = W2[i]; }
    if (t < D) { b1s[t] = b1[t]; b2s[t] = b2[t]; }
    float ep1 = 1.0f + eps[l];
    int local = t >> 5, j = t & 31;
    int node = blockIdx.x * 8 + local;
    __syncthreads();
    if (node < N)
        hs[local][j] = ep1 * x[(size_t)node * D + j] + aggr[(size_t)node * D + j];
    __syncthreads();
    if (node < N) {
        float acc = b1s[j];
        #pragma unroll
        for (int k = 0; k < D; ++k) acc = fmaf(hs[local][k], W1s[k * D + j], acc);
        y1s[local][j] = relu_f(acc);
    }
    __syncthreads();
    if (node < N) {
        float acc = b2s[j];
        #pragma unroll
        for (int k = 0; k < D; ++k) acc = fmaf(y1s[local][k], W2s[k * D + j], acc);
        out[(size_t)node * D + j] = relu_f(acc);
    }
}

// ============================== launcher ===============================
extern "C" void kernel_launch(void* const* d_in, const int* in_sizes, int n_in,
                              void* d_out, int out_size, void* d_ws, size_t ws_size,
                              hipStream_t stream) {
    const float* x_in = (const float*)d_in[0];
    const float* ea   = (const float*)d_in[1];
    const int*   ei   = (const int*)d_in[2];
    const float* W1   = (const float*)d_in[3];
    const float* b1   = (const float*)d_in[4];
    const float* W2   = (const float*)d_in[5];
    const float* b2   = (const float*)d_in[6];
    const float* eps  = (const float*)d_in[7];

    int N = in_sizes[0] / D;
    int E = in_sizes[1] / D;
    int L = in_sizes[3] / (D * D);

    const int* src = ei;       // edge_index[0] = message source j
    const int* dst = ei + E;   // edge_index[1] = message target i

    float* out = (float*)d_out;
    char*  ws  = (char*)d_ws;

    size_t off = 0;
    auto take = [&](size_t bytes) -> size_t {
        size_t p = off; off = (off + bytes + 255) & ~(size_t)255; return p;
    };
    size_t o_bufA    = take((size_t)N * D * sizeof(float));
    size_t o_row     = take((size_t)(N + 8) * sizeof(int));
    size_t o_part    = take(1024 * sizeof(int));
    size_t o_srcpk   = take((size_t)E * sizeof(int));
    size_t o_eperm   = take((size_t)E * sizeof(int));
    size_t need_csr  = off;
    size_t o_eah     = take((size_t)E * D * sizeof(unsigned short));
    size_t need_full = off;

    float* bufA  = (float*)(ws + o_bufA);
    int*   row   = (int*)(ws + o_row);
    int*   part  = (int*)(ws + o_part);
    int*   srcpk = (int*)(ws + o_srcpk);
    int*   eperm = (int*)(ws + o_eperm);

    int path = (ws_size >= need_full) ? 2 : (ws_size >= need_csr ? 1 : 0);

    if (path == 0) {
        float* aggr = bufA + (size_t)N * D;   // legacy path (needs 2*N*D)
        const float* cur = x_in;
        for (int l = 0; l < L; ++l) {
            float* nxt = (((L - 1 - l) & 1) == 0) ? out : bufA;
            hipMemsetAsync(aggr, 0, (size_t)N * D * sizeof(float), stream);
            gine_scatter_kernel<<<(E * 8 + 255) / 256, 256, 0, stream>>>(cur, ea, src, dst, aggr, E);
            gine_node_kernel<<<(N + 7) / 8, 256, 0, stream>>>(
                cur, aggr, W1 + (size_t)l * D * D, b1 + (size_t)l * D,
                W2 + (size_t)l * D * D, b2 + (size_t)l * D, eps, l, nxt, N);
            cur = nxt;
        }
        return;
    }

    unsigned* eah = (unsigned*)(ws + o_eah);

    // ---- preprocessing (once per call) ----
    int nb = (N + SCAN_CHUNK - 1) / SCAN_CHUNK;
    hipMemsetAsync(row, 0, (size_t)N * sizeof(int), stream);
    hist_kernel<<<(E + 255) / 256, 256, 0, stream>>>(dst, row, E);
    scan_partial_kernel<<<nb, 256, 0, stream>>>(row, part, N);
    scan_part_exclusive_kernel<<<1, 64, 0, stream>>>(part, nb);
    scan_final_kernel<<<nb, 256, 0, stream>>>(row, part, N);
    if (path == 2) {
        place_full_kernel<<<(E * 8 + 255) / 256, 256, 0, stream>>>(
            src, dst, ea, row, srcpk, eah, E);
    } else {
        place_csr_kernel<<<(E + 255) / 256, 256, 0, stream>>>(
            src, dst, row, srcpk, eperm, E);
    }
    // row[n] is now the inclusive prefix (end offset of node n)

    const float* cur = x_in;
    for (int l = 0; l < L; ++l) {
        float* nxt = (((L - 1 - l) & 1) == 0) ? out : bufA;
        if (path == 2) {
            gine_fused6_kernel<<<(N + NPB - 1) / NPB, 256, 0, stream>>>(
                cur, (const uint2*)eah, srcpk, row,
                W1 + (size_t)l * D * D, b1 + (size_t)l * D,
                W2 + (size_t)l * D * D, b2 + (size_t)l * D, eps, l, nxt, N);
        } else {
            gine_fused_kernel<<<(N + 7) / 8, 256, 0, stream>>>(
                cur, ea, srcpk, eperm, row,
                W1 + (size_t)l * D * D, b1 + (size_t)l * D,
                W2 + (size_t)l * D * D, b2 + (size_t)l * D, eps, l, nxt, N);
        }
        cur = nxt;
    }
}